// Round 2
// baseline (12178.200 us; speedup 1.0000x reference)
//
#include <hip/hip_runtime.h>
#include <math.h>

#define DIMK 1024
#define NDEPTH 4
#define DS 16
#define DCONV 4
#define DI 2048
#define DTR 64
#define NB 4
#define SL 2048
#define MT (NB * SL)        // 8192
#define NXZ (2 * DI)        // 4096
#define NDBC (DTR + 2 * DS) // 96

// ---------------------------------------------------------------------------
// C[m,n] = sum_k A[m*lda+k] * W[n*K+k].  M mult of 64, K mult of 16, N guarded.
__global__ __launch_bounds__(256) void gemm_nt(
    const float* __restrict__ A, const float* __restrict__ W,
    float* __restrict__ C, int M, int N, int K, int lda)
{
    __shared__ float As[16][68];
    __shared__ float Ws[16][68];
    const int bm = blockIdx.y * 64;
    const int bn = blockIdx.x * 64;
    const int tid = threadIdx.x;
    const int lr = tid >> 2;         // 0..63 tile row
    const int lk = (tid & 3) << 2;   // k sub-offset 0,4,8,12
    const int tm = (tid & 15) << 2;  // 0..60
    const int tn = (tid >> 4) << 2;  // 0..60
    float acc[4][4] = {};
    for (int k0 = 0; k0 < K; k0 += 16) {
        const float4 av = *(const float4*)(A + (size_t)(bm + lr) * lda + k0 + lk);
        float4 wv = make_float4(0.f, 0.f, 0.f, 0.f);
        if (bn + lr < N)
            wv = *(const float4*)(W + (size_t)(bn + lr) * K + k0 + lk);
        As[lk + 0][lr] = av.x; As[lk + 1][lr] = av.y;
        As[lk + 2][lr] = av.z; As[lk + 3][lr] = av.w;
        Ws[lk + 0][lr] = wv.x; Ws[lk + 1][lr] = wv.y;
        Ws[lk + 2][lr] = wv.z; Ws[lk + 3][lr] = wv.w;
        __syncthreads();
        #pragma unroll
        for (int kk = 0; kk < 16; ++kk) {
            const float4 a4 = *(const float4*)&As[kk][tm];
            const float4 w4 = *(const float4*)&Ws[kk][tn];
            const float a[4] = {a4.x, a4.y, a4.z, a4.w};
            const float w[4] = {w4.x, w4.y, w4.z, w4.w};
            #pragma unroll
            for (int i = 0; i < 4; ++i)
                #pragma unroll
                for (int j = 0; j < 4; ++j)
                    acc[i][j] = fmaf(a[i], w[j], acc[i][j]);
        }
        __syncthreads();
    }
    #pragma unroll
    for (int i = 0; i < 4; ++i) {
        const int m = bm + tm + i;
        #pragma unroll
        for (int j = 0; j < 4; ++j) {
            const int n = bn + tn + j;
            if (n < N)
                C[(size_t)m * N + n] = acc[i][j];
        }
    }
}

// ---------------------------------------------------------------------------
// xc[m,c] = silu( sum_j xi[m-3+j, c] * cw[c,j] + cb[c] ),  xi = xz[:, 0:DI]
// m is chunk-local; chunk is whole sequences so l = m & (SL-1).
__global__ __launch_bounds__(256) void conv_silu(
    const float* __restrict__ xz, const float* __restrict__ cw,
    const float* __restrict__ cb, float* __restrict__ xc)
{
    const int g = blockIdx.x * 256 + threadIdx.x;   // 0 .. M*DI/4
    const int c4 = g & (DI / 4 - 1);
    const int m = g >> 9;
    const int l = m & (SL - 1);
    const int c = c4 << 2;
    const float4 w0 = *(const float4*)(cw + (size_t)(c + 0) * DCONV);
    const float4 w1 = *(const float4*)(cw + (size_t)(c + 1) * DCONV);
    const float4 w2 = *(const float4*)(cw + (size_t)(c + 2) * DCONV);
    const float4 w3 = *(const float4*)(cw + (size_t)(c + 3) * DCONV);
    float4 acc = *(const float4*)(cb + c);
    #pragma unroll
    for (int j = 0; j < DCONV; ++j) {
        const int lj = l - 3 + j;
        if (lj >= 0) {
            const float4 v = *(const float4*)(xz + (size_t)(m - 3 + j) * NXZ + c);
            acc.x = fmaf(v.x, (&w0.x)[j], acc.x);
            acc.y = fmaf(v.y, (&w1.x)[j], acc.y);
            acc.z = fmaf(v.z, (&w2.x)[j], acc.z);
            acc.w = fmaf(v.w, (&w3.x)[j], acc.w);
        }
    }
    acc.x = acc.x / (1.f + __expf(-acc.x));
    acc.y = acc.y / (1.f + __expf(-acc.y));
    acc.z = acc.z / (1.f + __expf(-acc.z));
    acc.w = acc.w / (1.f + __expf(-acc.w));
    *(float4*)(xc + (size_t)m * DI + c) = acc;
}

// ---------------------------------------------------------------------------
// Selective scan with on-the-fly delta. Block = 256 = 16 channels x 16 states.
// delta[m,c] = softplus(dot(dbc[m,0:64], dtw[c,:]) + dtb[c]) computed via
// 4-FMA partials + shfl_xor reduce over the 16 state lanes.
// Fuses +u*D and *silu(z). y is written into the (dead) xi half of xz.
__global__ __launch_bounds__(256) void scan_k(
    const float* __restrict__ u,     // xc [M, DI]
    const float* __restrict__ dbc,   // [M, NDBC]: dt 0..63, B 64..79, C 80..95
    float* __restrict__ xz,          // z read at col DI+c, y written at col c
    const float* __restrict__ Alog,  // [DI, DS] layer slice
    const float* __restrict__ Dl,    // [DI]
    const float* __restrict__ dtw,   // [DI, DTR]
    const float* __restrict__ dtb)   // [DI]
{
    const int b = blockIdx.y;        // chunk-local sequence
    const int c0 = blockIdx.x * 16;
    const int tid = threadIdx.x;
    const int ch = tid >> 4;
    const int s = tid & 15;
    const int c = c0 + ch;
    const float Aa = -__expf(Alog[(size_t)c * DS + s]);
    const float Dc = Dl[c];
    const float4 w4 = *(const float4*)(dtw + (size_t)c * DTR + 4 * s);
    const float bdt = dtb[c];
    __shared__ float sdbc[64][96];
    __shared__ float su[64][16], sz[64][16], sy[64][16];
    float h = 0.f;
    const int row = tid >> 2;
    const int q = (tid & 3) << 2;
    for (int t0 = 0; t0 < SL; t0 += 64) {
        const size_t mb = (size_t)b * SL + t0;
        *(float4*)&su[row][q] = *(const float4*)(u + (mb + row) * DI + c0 + q);
        *(float4*)&sz[row][q] = *(const float4*)(xz + (mb + row) * NXZ + DI + c0 + q);
        #pragma unroll
        for (int p = 0; p < 6; ++p) {
            const int idx = p * 256 + tid;
            const int r2 = idx / 24;
            const int q2 = (idx % 24) * 4;
            *(float4*)&sdbc[r2][q2] = *(const float4*)(dbc + (mb + r2) * NDBC + q2);
        }
        __syncthreads();
        for (int t = 0; t < 64; ++t) {
            const float* dr = sdbc[t];
            const float4 dt4 = *(const float4*)&dr[4 * s];
            float pd = w4.x * dt4.x;
            pd = fmaf(w4.y, dt4.y, pd);
            pd = fmaf(w4.z, dt4.z, pd);
            pd = fmaf(w4.w, dt4.w, pd);
            pd += __shfl_xor(pd, 1, 16);
            pd += __shfl_xor(pd, 2, 16);
            pd += __shfl_xor(pd, 4, 16);
            pd += __shfl_xor(pd, 8, 16);
            float dl = pd + bdt;
            dl = (dl > 20.f) ? dl : log1pf(__expf(dl));
            const float uu = su[t][ch];
            const float dA = __expf(dl * Aa);
            h = fmaf(dA, h, dl * uu * dr[DTR + s]);        // h = dA*h + dl*u*B_s
            float py = h * dr[DTR + DS + s];
            py += __shfl_xor(py, 1, 16);
            py += __shfl_xor(py, 2, 16);
            py += __shfl_xor(py, 4, 16);
            py += __shfl_xor(py, 8, 16);
            if (s == 0) {
                const float zz = sz[t][ch];
                sy[t][ch] = (py + uu * Dc) * (zz / (1.f + __expf(-zz)));
            }
        }
        __syncthreads();
        *(float4*)(xz + (mb + row) * NXZ + c0 + q) = *(const float4*)&sy[row][q];
        __syncthreads();
    }
}

// ---------------------------------------------------------------------------
extern "C" void kernel_launch(void* const* d_in, const int* in_sizes, int n_in,
                              void* d_out, int out_size, void* d_ws, size_t ws_size,
                              hipStream_t stream)
{
    const float* x0   = (const float*)d_in[0];
    const float* in_w = (const float*)d_in[1];
    const float* cw   = (const float*)d_in[2];
    const float* cb   = (const float*)d_in[3];
    const float* xpw  = (const float*)d_in[4];
    const float* dtw  = (const float*)d_in[5];
    const float* dtb  = (const float*)d_in[6];
    const float* Alog = (const float*)d_in[7];
    const float* Dp   = (const float*)d_in[8];
    const float* ow   = (const float*)d_in[9];
    float* xbuf = (float*)d_out;     // inter-layer x lives in d_out (MT*DIMK)

    // per-sequence ws need (floats): xz SL*NXZ + xc SL*DI + dbc SL*NDBC
    const size_t perB = (size_t)SL * (NXZ + DI + NDBC) * sizeof(float); // ~51.1MB
    int nbc = 1;
    if (ws_size >= perB * 4) nbc = 4;
    else if (ws_size >= perB * 2) nbc = 2;
    const int nchunks = NB / nbc;
    const int M = nbc * SL;

    float* xz  = (float*)d_ws;
    float* xc  = xz + (size_t)M * NXZ;
    float* dbc = xc + (size_t)M * DI;

    const dim3 blk(256);
    for (int ly = 0; ly < NDEPTH; ++ly) {
        const float* Wi   = in_w + (size_t)ly * NXZ * DIMK;
        const float* cwl  = cw   + (size_t)ly * DI * DCONV;
        const float* cbl  = cb   + (size_t)ly * DI;
        const float* xpl  = xpw  + (size_t)ly * NDBC * DI;
        const float* dtwl = dtw  + (size_t)ly * DI * DTR;
        const float* dtbl = dtb  + (size_t)ly * DI;
        const float* Al   = Alog + (size_t)ly * DI * DS;
        const float* Dl   = Dp   + (size_t)ly * DI;
        const float* owl  = ow   + (size_t)ly * DIMK * DI;

        for (int ck = 0; ck < nchunks; ++ck) {
            const float* xin = (ly == 0 ? x0 : xbuf) + (size_t)ck * M * DIMK;
            float* xdst = xbuf + (size_t)ck * M * DIMK;
            // 1. xz = x @ Wi^T
            gemm_nt<<<dim3(NXZ / 64, M / 64), blk, 0, stream>>>(
                xin, Wi, xz, M, NXZ, DIMK, DIMK);
            // 2. xc = silu(causal depthwise conv(xi) + cb)
            conv_silu<<<dim3(M * (DI / 4) / 256), blk, 0, stream>>>(xz, cwl, cbl, xc);
            // 3. dbc = xc @ xp^T
            gemm_nt<<<dim3(2, M / 64), blk, 0, stream>>>(
                xc, xpl, dbc, M, NDBC, DI, DI);
            // 4+5. delta on the fly + selective scan; y -> xi half of xz
            scan_k<<<dim3(DI / 16, nbc), blk, 0, stream>>>(
                xc, dbc, xz, Al, Dl, dtwl, dtbl);
            // 6. x_next(out) = y @ ow^T
            gemm_nt<<<dim3(DIMK / 64, M / 64), blk, 0, stream>>>(
                xz, owl, xdst, M, DIMK, DI, NXZ);
        }
    }
}

// Round 3
// 4098.271 us; speedup vs baseline: 2.9715x; 2.9715x over previous
//
#include <hip/hip_runtime.h>
#include <math.h>

#define DIMK 1024
#define NDEPTH 4
#define DS 16
#define DCONV 4
#define DI 2048
#define DTR 64
#define NB 4
#define SL 2048
#define MT (NB * SL)        // 8192
#define NXZ (2 * DI)        // 4096
#define NDBC (DTR + 2 * DS) // 96

typedef float f32x4 __attribute__((ext_vector_type(4)));
typedef short short8 __attribute__((ext_vector_type(8)));

__device__ inline unsigned short f2bf(float f) {
    unsigned u = __builtin_bit_cast(unsigned, f);
    unsigned r = (u + 0x7FFFu + ((u >> 16) & 1u)) >> 16;
    return (unsigned short)r;
}

__device__ inline void mfma16(f32x4& d, short8 a, short8 b) {
    asm volatile("v_mfma_f32_16x16x32_bf16 %0, %1, %2, %0"
                 : "+v"(d) : "v"(a), "v"(b));
}

// ---------------------------------------------------------------------------
// C[m,n] = sum_k A[m,k]*W[n,k], bf16 MFMA, fp32 in/out (cvt fused in staging).
// M%128==0, N%128==0, K%32==0.
__global__ __launch_bounds__(256) void gemm_mfma(
    const float* __restrict__ A, const float* __restrict__ W,
    float* __restrict__ C, int K, int lda, int ldc)
{
    __shared__ unsigned short As[128 * 32];
    __shared__ unsigned short Ws[128 * 32];
    const int tid = threadIdx.x;
    const int bm = blockIdx.y * 128;
    const int bn = blockIdx.x * 128;
    const int r = tid >> 1;          // staging row 0..127
    const int h = tid & 1;           // k-half
    const int wv = tid >> 6;
    const int wr = wv >> 1;          // wave row 0..1
    const int wc = wv & 1;           // wave col 0..1
    const int ln = tid & 63;
    const int fr = ln & 15;
    const int kg = ln >> 4;
    f32x4 acc[4][4] = {};
    const float* ga = A + (size_t)(bm + r) * lda + h * 16;
    const float* gw = W + (size_t)(bn + r) * K + h * 16;
    for (int k0 = 0; k0 < K; k0 += 32) {
        #pragma unroll
        for (int p = 0; p < 2; ++p) {
            const int pk = (2 * h + p) ^ ((r >> 1) & 3);
            float4 f0 = *(const float4*)(ga + k0 + p * 8);
            float4 f1 = *(const float4*)(ga + k0 + p * 8 + 4);
            short8 v;
            v[0] = (short)f2bf(f0.x); v[1] = (short)f2bf(f0.y);
            v[2] = (short)f2bf(f0.z); v[3] = (short)f2bf(f0.w);
            v[4] = (short)f2bf(f1.x); v[5] = (short)f2bf(f1.y);
            v[6] = (short)f2bf(f1.z); v[7] = (short)f2bf(f1.w);
            *(short8*)&As[r * 32 + pk * 8] = v;
            f0 = *(const float4*)(gw + k0 + p * 8);
            f1 = *(const float4*)(gw + k0 + p * 8 + 4);
            v[0] = (short)f2bf(f0.x); v[1] = (short)f2bf(f0.y);
            v[2] = (short)f2bf(f0.z); v[3] = (short)f2bf(f0.w);
            v[4] = (short)f2bf(f1.x); v[5] = (short)f2bf(f1.y);
            v[6] = (short)f2bf(f1.z); v[7] = (short)f2bf(f1.w);
            *(short8*)&Ws[r * 32 + pk * 8] = v;
        }
        __syncthreads();
        short8 af[4], bw[4];
        #pragma unroll
        for (int f = 0; f < 4; ++f) {
            const int ra = wr * 64 + f * 16 + fr;
            af[f] = *(const short8*)&As[ra * 32 + ((kg ^ ((ra >> 1) & 3)) * 8)];
            const int rb = wc * 64 + f * 16 + fr;
            bw[f] = *(const short8*)&Ws[rb * 32 + ((kg ^ ((rb >> 1) & 3)) * 8)];
        }
        #pragma unroll
        for (int fi = 0; fi < 4; ++fi)
            #pragma unroll
            for (int fj = 0; fj < 4; ++fj)
                mfma16(acc[fi][fj], af[fi], bw[fj]);
        __syncthreads();
    }
    #pragma unroll
    for (int fi = 0; fi < 4; ++fi) {
        const int m0 = bm + wr * 64 + fi * 16 + kg * 4;
        #pragma unroll
        for (int fj = 0; fj < 4; ++fj) {
            const int n = bn + wc * 64 + fj * 16 + fr;
            #pragma unroll
            for (int q = 0; q < 4; ++q)
                C[(size_t)(m0 + q) * ldc + n] = acc[fi][fj][q];
        }
    }
}

// ---------------------------------------------------------------------------
// fp32 fallback GEMM. EPI 0: none. EPI 1: softplus(v + bias[n]).
// M%64==0, K%16==0, N guarded.
template <int EPI>
__global__ __launch_bounds__(256) void gemm_nt(
    const float* __restrict__ A, const float* __restrict__ W,
    float* __restrict__ C, int N, int K, int lda, int ldc,
    const float* __restrict__ bias)
{
    __shared__ float As[16][68];
    __shared__ float Ws[16][68];
    const int bm = blockIdx.y * 64;
    const int bn = blockIdx.x * 64;
    const int tid = threadIdx.x;
    const int lr = tid >> 2;
    const int lk = (tid & 3) << 2;
    const int tm = (tid & 15) << 2;
    const int tn = (tid >> 4) << 2;
    float acc[4][4] = {};
    for (int k0 = 0; k0 < K; k0 += 16) {
        const float4 av = *(const float4*)(A + (size_t)(bm + lr) * lda + k0 + lk);
        float4 wv = make_float4(0.f, 0.f, 0.f, 0.f);
        if (bn + lr < N)
            wv = *(const float4*)(W + (size_t)(bn + lr) * K + k0 + lk);
        As[lk + 0][lr] = av.x; As[lk + 1][lr] = av.y;
        As[lk + 2][lr] = av.z; As[lk + 3][lr] = av.w;
        Ws[lk + 0][lr] = wv.x; Ws[lk + 1][lr] = wv.y;
        Ws[lk + 2][lr] = wv.z; Ws[lk + 3][lr] = wv.w;
        __syncthreads();
        #pragma unroll
        for (int kk = 0; kk < 16; ++kk) {
            const float4 a4 = *(const float4*)&As[kk][tm];
            const float4 w4 = *(const float4*)&Ws[kk][tn];
            const float a[4] = {a4.x, a4.y, a4.z, a4.w};
            const float w[4] = {w4.x, w4.y, w4.z, w4.w};
            #pragma unroll
            for (int i = 0; i < 4; ++i)
                #pragma unroll
                for (int j = 0; j < 4; ++j)
                    acc[i][j] = fmaf(a[i], w[j], acc[i][j]);
        }
        __syncthreads();
    }
    #pragma unroll
    for (int i = 0; i < 4; ++i) {
        const int m = bm + tm + i;
        #pragma unroll
        for (int j = 0; j < 4; ++j) {
            const int n = bn + tn + j;
            if (n < N) {
                float v = acc[i][j];
                if (EPI == 1) {
                    v += bias[n];
                    v = (v > 20.f) ? v : log1pf(__expf(v));
                }
                C[(size_t)m * ldc + n] = v;
            }
        }
    }
}

// ---------------------------------------------------------------------------
__global__ __launch_bounds__(256) void conv_silu(
    const float* __restrict__ xz, const float* __restrict__ cw,
    const float* __restrict__ cb, float* __restrict__ xc)
{
    const int g = blockIdx.x * 256 + threadIdx.x;
    const int c4 = g & (DI / 4 - 1);
    const int m = g >> 9;
    const int l = m & (SL - 1);
    const int c = c4 << 2;
    const float4 w0 = *(const float4*)(cw + (size_t)(c + 0) * DCONV);
    const float4 w1 = *(const float4*)(cw + (size_t)(c + 1) * DCONV);
    const float4 w2 = *(const float4*)(cw + (size_t)(c + 2) * DCONV);
    const float4 w3 = *(const float4*)(cw + (size_t)(c + 3) * DCONV);
    float4 acc = *(const float4*)(cb + c);
    #pragma unroll
    for (int j = 0; j < DCONV; ++j) {
        const int lj = l - 3 + j;
        if (lj >= 0) {
            const float4 v = *(const float4*)(xz + (size_t)(m - 3 + j) * NXZ + c);
            acc.x = fmaf(v.x, (&w0.x)[j], acc.x);
            acc.y = fmaf(v.y, (&w1.x)[j], acc.y);
            acc.z = fmaf(v.z, (&w2.x)[j], acc.z);
            acc.w = fmaf(v.w, (&w3.x)[j], acc.w);
        }
    }
    acc.x = acc.x / (1.f + __expf(-acc.x));
    acc.y = acc.y / (1.f + __expf(-acc.y));
    acc.z = acc.z / (1.f + __expf(-acc.z));
    acc.w = acc.w / (1.f + __expf(-acc.w));
    *(float4*)(xc + (size_t)m * DI + c) = acc;
}

// ---------------------------------------------------------------------------
// Selective scan, slim t-loop. delta precomputed by GEMM (xi half of xz).
// y overwrites u (=xc): block owns channel cols [c0,c0+16) exclusively.
__global__ __launch_bounds__(256) void scan_k(
    const float* __restrict__ u,    // xc [M, DI]
    const float* __restrict__ dbc,  // [M, 96]: B 64..79, C 80..95
    const float* __restrict__ xz,   // delta at col c, z at col DI+c
    float* __restrict__ y,          // = xc
    const float* __restrict__ Alog, // [DI, DS] layer slice
    const float* __restrict__ Dl)   // [DI]
{
    const int b = blockIdx.y;
    const int c0 = blockIdx.x * 16;
    const int tid = threadIdx.x;
    const int ch = tid >> 4;
    const int s = tid & 15;
    const float Aa = -__expf(Alog[(size_t)(c0 + ch) * DS + s]);
    __shared__ float sD[16];
    __shared__ float sdl[64][16], sxb[64][16], sp0[64][16], sp1[64][16], sy[64][16];
    __shared__ float sbc[64][32];
    if (tid < 16) sD[tid] = Dl[c0 + tid];
    float h = 0.f;
    const int row = tid >> 2;
    const int q = (tid & 3) << 2;
    __syncthreads();
    for (int t0 = 0; t0 < SL; t0 += 64) {
        const size_t mb = (size_t)b * SL + t0;
        const float4 dlv = *(const float4*)(xz + (mb + row) * NXZ + c0 + q);
        const float4 uv  = *(const float4*)(u  + (mb + row) * DI  + c0 + q);
        const float4 zv  = *(const float4*)(xz + (mb + row) * NXZ + DI + c0 + q);
        float4 xb, p0, p1;
        #pragma unroll
        for (int j = 0; j < 4; ++j) {
            const float dl = (&dlv.x)[j], uu = (&uv.x)[j], zz = (&zv.x)[j];
            const float w = zz / (1.f + __expf(-zz));
            (&xb.x)[j] = dl * uu;
            (&p1.x)[j] = w;
            (&p0.x)[j] = uu * sD[q + j] * w;
        }
        *(float4*)&sdl[row][q] = dlv;
        *(float4*)&sxb[row][q] = xb;
        *(float4*)&sp0[row][q] = p0;
        *(float4*)&sp1[row][q] = p1;
        #pragma unroll
        for (int p = 0; p < 2; ++p) {
            const int idx = p * 256 + tid;
            const int r2 = idx >> 3, q2 = (idx & 7) << 2;
            *(float4*)&sbc[r2][q2] = *(const float4*)(dbc + (mb + r2) * NDBC + DTR + q2);
        }
        __syncthreads();
        #pragma unroll 4
        for (int t = 0; t < 64; ++t) {
            const float dA = __expf(sdl[t][ch] * Aa);
            h = fmaf(dA, h, sxb[t][ch] * sbc[t][s]);
            float py = h * sbc[t][16 + s];
            py += __shfl_xor(py, 1, 16);
            py += __shfl_xor(py, 2, 16);
            py += __shfl_xor(py, 4, 16);
            py += __shfl_xor(py, 8, 16);
            if (s == 0)
                sy[t][ch] = fmaf(py, sp1[t][ch], sp0[t][ch]);
        }
        __syncthreads();
        *(float4*)(y + (mb + row) * DI + c0 + q) = *(const float4*)&sy[row][q];
        __syncthreads();
    }
}

// ---------------------------------------------------------------------------
extern "C" void kernel_launch(void* const* d_in, const int* in_sizes, int n_in,
                              void* d_out, int out_size, void* d_ws, size_t ws_size,
                              hipStream_t stream)
{
    const float* x0   = (const float*)d_in[0];
    const float* in_w = (const float*)d_in[1];
    const float* cw   = (const float*)d_in[2];
    const float* cb   = (const float*)d_in[3];
    const float* xpw  = (const float*)d_in[4];
    const float* dtw  = (const float*)d_in[5];
    const float* dtb  = (const float*)d_in[6];
    const float* Alog = (const float*)d_in[7];
    const float* Dp   = (const float*)d_in[8];
    const float* ow   = (const float*)d_in[9];
    float* xbuf = (float*)d_out;  // inter-layer x lives in d_out (MT*DIMK)

    const size_t perB = (size_t)SL * (NXZ + DI + NDBC) * sizeof(float); // ~51.1MB
    int nbc = 1;
    if (ws_size >= perB * 4) nbc = 4;
    else if (ws_size >= perB * 2) nbc = 2;
    else if (ws_size < perB) return;
    const int nchunks = NB / nbc;
    const int M = nbc * SL;

    float* xz  = (float*)d_ws;                 // [M, NXZ]; xi half reused as delta
    float* xc  = xz + (size_t)M * NXZ;         // [M, DI];  reused as y
    float* dbc = xc + (size_t)M * DI;          // [M, NDBC]

    const dim3 blk(256);
    for (int ly = 0; ly < NDEPTH; ++ly) {
        const float* Wi   = in_w + (size_t)ly * NXZ * DIMK;
        const float* cwl  = cw   + (size_t)ly * DI * DCONV;
        const float* cbl  = cb   + (size_t)ly * DI;
        const float* xpl  = xpw  + (size_t)ly * NDBC * DI;
        const float* dtwl = dtw  + (size_t)ly * DI * DTR;
        const float* dtbl = dtb  + (size_t)ly * DI;
        const float* Al   = Alog + (size_t)ly * DI * DS;
        const float* Dl   = Dp   + (size_t)ly * DI;
        const float* owl  = ow   + (size_t)ly * DIMK * DI;

        for (int ck = 0; ck < nchunks; ++ck) {
            const float* xin = (ly == 0 ? x0 : xbuf) + (size_t)ck * M * DIMK;
            float* xdst = xbuf + (size_t)ck * M * DIMK;
            // 1. xz = x @ Wi^T  (bf16 MFMA)
            gemm_mfma<<<dim3(NXZ / 128, M / 128), blk, 0, stream>>>(
                xin, Wi, xz, DIMK, DIMK, NXZ);
            // 2. xc = silu(causal depthwise conv(xi) + cb)
            conv_silu<<<dim3(M * (DI / 4) / 256), blk, 0, stream>>>(xz, cwl, cbl, xc);
            // 3. dbc = xc @ xp^T  (fp32, N=96)
            gemm_nt<0><<<dim3(2, M / 64), blk, 0, stream>>>(
                xc, xpl, dbc, NDBC, DI, DI, NDBC, nullptr);
            // 4. delta = softplus(dt @ dtw^T + dtb) -> xi half of xz (fp32, K=64)
            gemm_nt<1><<<dim3(DI / 64, M / 64), blk, 0, stream>>>(
                dbc, dtwl, xz, DI, DTR, NDBC, NXZ, dtbl);
            // 5. scan; y -> xc
            scan_k<<<dim3(DI / 16, nbc), blk, 0, stream>>>(
                xc, dbc, xz, xc, Al, Dl);
            // 6. x_next = y @ ow^T  (bf16 MFMA)
            gemm_mfma<<<dim3(DIMK / 128, M / 128), blk, 0, stream>>>(
                xc, owl, xdst, DI, DI, DIMK);
        }
    }
}

// Round 4
// 2817.009 us; speedup vs baseline: 4.3231x; 1.4548x over previous
//
#include <hip/hip_runtime.h>
#include <math.h>

#define DIMK 1024
#define NDEPTH 4
#define DS 16
#define DCONV 4
#define DI 2048
#define DTR 64
#define NB 4
#define SL 2048
#define MT (NB * SL)        // 8192
#define NXZ (2 * DI)        // 4096
#define NDBC (DTR + 2 * DS) // 96

typedef float f32x4 __attribute__((ext_vector_type(4)));
typedef short short8 __attribute__((ext_vector_type(8)));
typedef short short4v __attribute__((ext_vector_type(4)));

__device__ inline unsigned short f2bf(float f) {
    unsigned u = __builtin_bit_cast(unsigned, f);
    unsigned r = (u + 0x7FFFu + ((u >> 16) & 1u)) >> 16;
    return (unsigned short)r;
}
__device__ inline float bf2f(unsigned short h) {
    unsigned u = ((unsigned)h) << 16;
    return __builtin_bit_cast(float, u);
}
__device__ inline void split_bf(float f, unsigned short& hi, unsigned short& lo) {
    hi = f2bf(f);
    lo = f2bf(f - bf2f(hi));
}
__device__ inline void mfma16(f32x4& d, short8 a, short8 b) {
    asm volatile("v_mfma_f32_16x16x32_bf16 %0, %1, %2, %0"
                 : "+v"(d) : "v"(a), "v"(b));
}
// add value moved by DPP (VALU pipe, within 16-lane row)
template <int CTRL>
__device__ inline float dpp_radd(float v) {
    int x = __builtin_bit_cast(int, v);
    int m = __builtin_amdgcn_update_dpp(0, x, CTRL, 0xF, 0xF, false);
    return v + __builtin_bit_cast(float, m);
}

// ---------------------------------------------------------------------------
// C[m,n] = sum_k A[m,k]*W[n,k], plain bf16 MFMA (main x-chain GEMMs).
__global__ __launch_bounds__(256) void gemm_mfma(
    const float* __restrict__ A, const float* __restrict__ W,
    float* __restrict__ C, int K, int lda, int ldc)
{
    __shared__ unsigned short As[128 * 32];
    __shared__ unsigned short Ws[128 * 32];
    const int tid = threadIdx.x;
    const int bm = blockIdx.y * 128;
    const int bn = blockIdx.x * 128;
    const int r = tid >> 1;
    const int h = tid & 1;
    const int wv = tid >> 6;
    const int wr = wv >> 1;
    const int wc = wv & 1;
    const int ln = tid & 63;
    const int fr = ln & 15;
    const int kg = ln >> 4;
    f32x4 acc[4][4] = {};
    const float* ga = A + (size_t)(bm + r) * lda + h * 16;
    const float* gw = W + (size_t)(bn + r) * K + h * 16;
    for (int k0 = 0; k0 < K; k0 += 32) {
        #pragma unroll
        for (int p = 0; p < 2; ++p) {
            const int pk = (2 * h + p) ^ ((r >> 1) & 3);
            float4 f0 = *(const float4*)(ga + k0 + p * 8);
            float4 f1 = *(const float4*)(ga + k0 + p * 8 + 4);
            short8 v;
            v[0] = (short)f2bf(f0.x); v[1] = (short)f2bf(f0.y);
            v[2] = (short)f2bf(f0.z); v[3] = (short)f2bf(f0.w);
            v[4] = (short)f2bf(f1.x); v[5] = (short)f2bf(f1.y);
            v[6] = (short)f2bf(f1.z); v[7] = (short)f2bf(f1.w);
            *(short8*)&As[r * 32 + pk * 8] = v;
            f0 = *(const float4*)(gw + k0 + p * 8);
            f1 = *(const float4*)(gw + k0 + p * 8 + 4);
            v[0] = (short)f2bf(f0.x); v[1] = (short)f2bf(f0.y);
            v[2] = (short)f2bf(f0.z); v[3] = (short)f2bf(f0.w);
            v[4] = (short)f2bf(f1.x); v[5] = (short)f2bf(f1.y);
            v[6] = (short)f2bf(f1.z); v[7] = (short)f2bf(f1.w);
            *(short8*)&Ws[r * 32 + pk * 8] = v;
        }
        __syncthreads();
        short8 af[4], bw[4];
        #pragma unroll
        for (int f = 0; f < 4; ++f) {
            const int ra = wr * 64 + f * 16 + fr;
            af[f] = *(const short8*)&As[ra * 32 + ((kg ^ ((ra >> 1) & 3)) * 8)];
            const int rb = wc * 64 + f * 16 + fr;
            bw[f] = *(const short8*)&Ws[rb * 32 + ((kg ^ ((rb >> 1) & 3)) * 8)];
        }
        #pragma unroll
        for (int fi = 0; fi < 4; ++fi)
            #pragma unroll
            for (int fj = 0; fj < 4; ++fj)
                mfma16(acc[fi][fj], af[fi], bw[fj]);
        __syncthreads();
    }
    #pragma unroll
    for (int fi = 0; fi < 4; ++fi) {
        const int m0 = bm + wr * 64 + fi * 16 + kg * 4;
        #pragma unroll
        for (int fj = 0; fj < 4; ++fj) {
            const int n = bn + wc * 64 + fj * 16 + fr;
            #pragma unroll
            for (int q = 0; q < 4; ++q)
                C[(size_t)(m0 + q) * ldc + n] = acc[fi][fj][q];
        }
    }
}

// ---------------------------------------------------------------------------
// dbc = xc @ xp^T, hi/lo-split bf16 MFMA (~fp32 accuracy). BM=128, BN=32.
__global__ __launch_bounds__(256) void gemm_xproj(
    const float* __restrict__ A, const float* __restrict__ W,
    float* __restrict__ C, int K, int lda)
{
    __shared__ unsigned short Ah[128 * 32], Al[128 * 32];
    __shared__ unsigned short Wh[32 * 32], Wl[32 * 32];
    const int tid = threadIdx.x;
    const int bm = blockIdx.y * 128;
    const int bn = blockIdx.x * 32;
    const int r = tid >> 1, hf = tid & 1;
    const int wv = tid >> 6;
    const int ln = tid & 63, fr = ln & 15, kg = ln >> 4;
    const int wsr = tid >> 3;          // W stage row 0..31
    const int wc4 = (tid & 7) << 2;    // W stage col 0,4,..,28
    f32x4 acc[2][2] = {};
    const float* ga = A + (size_t)(bm + r) * lda + hf * 16;
    const float* gw = W + (size_t)(bn + wsr) * K + wc4;
    for (int k0 = 0; k0 < K; k0 += 32) {
        #pragma unroll
        for (int j = 0; j < 4; ++j) {
            const int col = hf * 16 + j * 4;
            const int ad = r * 32 + (((col >> 3) ^ ((r >> 1) & 3)) << 3) + (col & 7);
            const float4 fa = *(const float4*)(ga + k0 + j * 4);
            short4v h4, l4;
            #pragma unroll
            for (int e = 0; e < 4; ++e) {
                unsigned short hh, llo;
                split_bf((&fa.x)[e], hh, llo);
                h4[e] = (short)hh; l4[e] = (short)llo;
            }
            *(short4v*)&Ah[ad] = h4;
            *(short4v*)&Al[ad] = l4;
        }
        {
            const int ad = wsr * 32 + (((wc4 >> 3) ^ ((wsr >> 1) & 3)) << 3) + (wc4 & 7);
            const float4 fw = *(const float4*)(gw + k0);
            short4v h4, l4;
            #pragma unroll
            for (int e = 0; e < 4; ++e) {
                unsigned short hh, llo;
                split_bf((&fw.x)[e], hh, llo);
                h4[e] = (short)hh; l4[e] = (short)llo;
            }
            *(short4v*)&Wh[ad] = h4;
            *(short4v*)&Wl[ad] = l4;
        }
        __syncthreads();
        short8 ah[2], alo[2], bh[2], bl[2];
        #pragma unroll
        for (int f = 0; f < 2; ++f) {
            const int ra = wv * 32 + f * 16 + fr;
            const int ao = ra * 32 + ((kg ^ ((ra >> 1) & 3)) * 8);
            ah[f]  = *(const short8*)&Ah[ao];
            alo[f] = *(const short8*)&Al[ao];
            const int rb = f * 16 + fr;
            const int bo = rb * 32 + ((kg ^ ((rb >> 1) & 3)) * 8);
            bh[f] = *(const short8*)&Wh[bo];
            bl[f] = *(const short8*)&Wl[bo];
        }
        #pragma unroll
        for (int fi = 0; fi < 2; ++fi)
            #pragma unroll
            for (int fj = 0; fj < 2; ++fj) {
                mfma16(acc[fi][fj], ah[fi], bh[fj]);
                mfma16(acc[fi][fj], ah[fi], bl[fj]);
                mfma16(acc[fi][fj], alo[fi], bh[fj]);
            }
        __syncthreads();
    }
    #pragma unroll
    for (int fi = 0; fi < 2; ++fi) {
        const int m0 = bm + wv * 32 + fi * 16 + kg * 4;
        #pragma unroll
        for (int fj = 0; fj < 2; ++fj) {
            const int n = bn + fj * 16 + fr;
            #pragma unroll
            for (int q = 0; q < 4; ++q)
                C[(size_t)(m0 + q) * NDBC + n] = acc[fi][fj][q];
        }
    }
}

// ---------------------------------------------------------------------------
// delta = softplus(dt @ dtw^T + dtb) -> xi half of xz. Split MFMA, K=64.
__global__ __launch_bounds__(256) void gemm_delta(
    const float* __restrict__ A,   // dbc, lda=NDBC, cols 0..63
    const float* __restrict__ W,   // dtw [DI, 64]
    float* __restrict__ C,         // xz, ldc=NXZ
    const float* __restrict__ bias)
{
    __shared__ unsigned short Ah[128 * 32], Al[128 * 32];
    __shared__ unsigned short Wh[128 * 32], Wl[128 * 32];
    const int tid = threadIdx.x;
    const int bm = blockIdx.y * 128;
    const int bn = blockIdx.x * 128;
    const int r = tid >> 1, hf = tid & 1;
    const int wv = tid >> 6, wr = wv >> 1, wc = wv & 1;
    const int ln = tid & 63, fr = ln & 15, kg = ln >> 4;
    f32x4 acc[4][4] = {};
    const float* ga = A + (size_t)(bm + r) * NDBC + hf * 16;
    const float* gw = W + (size_t)(bn + r) * DTR + hf * 16;
    for (int k0 = 0; k0 < DTR; k0 += 32) {
        #pragma unroll
        for (int j = 0; j < 4; ++j) {
            const int col = hf * 16 + j * 4;
            const int ad = r * 32 + (((col >> 3) ^ ((r >> 1) & 3)) << 3) + (col & 7);
            const float4 fa = *(const float4*)(ga + k0 + j * 4);
            const float4 fw = *(const float4*)(gw + k0 + j * 4);
            short4v ah4, al4, wh4, wl4;
            #pragma unroll
            for (int e = 0; e < 4; ++e) {
                unsigned short hh, llo;
                split_bf((&fa.x)[e], hh, llo);
                ah4[e] = (short)hh; al4[e] = (short)llo;
                split_bf((&fw.x)[e], hh, llo);
                wh4[e] = (short)hh; wl4[e] = (short)llo;
            }
            *(short4v*)&Ah[ad] = ah4; *(short4v*)&Al[ad] = al4;
            *(short4v*)&Wh[ad] = wh4; *(short4v*)&Wl[ad] = wl4;
        }
        __syncthreads();
        short8 ah[4], alo[4], bh[4], bl[4];
        #pragma unroll
        for (int f = 0; f < 4; ++f) {
            const int ra = wr * 64 + f * 16 + fr;
            const int ao = ra * 32 + ((kg ^ ((ra >> 1) & 3)) * 8);
            ah[f]  = *(const short8*)&Ah[ao];
            alo[f] = *(const short8*)&Al[ao];
            const int rb = wc * 64 + f * 16 + fr;
            const int bo = rb * 32 + ((kg ^ ((rb >> 1) & 3)) * 8);
            bh[f] = *(const short8*)&Wh[bo];
            bl[f] = *(const short8*)&Wl[bo];
        }
        #pragma unroll
        for (int fi = 0; fi < 4; ++fi)
            #pragma unroll
            for (int fj = 0; fj < 4; ++fj) {
                mfma16(acc[fi][fj], ah[fi], bh[fj]);
                mfma16(acc[fi][fj], ah[fi], bl[fj]);
                mfma16(acc[fi][fj], alo[fi], bh[fj]);
            }
        __syncthreads();
    }
    #pragma unroll
    for (int fi = 0; fi < 4; ++fi) {
        const int m0 = bm + wr * 64 + fi * 16 + kg * 4;
        #pragma unroll
        for (int fj = 0; fj < 4; ++fj) {
            const int n = bn + wc * 64 + fj * 16 + fr;
            const float bb = bias[n];
            #pragma unroll
            for (int q = 0; q < 4; ++q) {
                float v = acc[fi][fj][q] + bb;
                v = (v > 20.f) ? v : log1pf(__expf(v));
                C[(size_t)(m0 + q) * NXZ + n] = v;
            }
        }
    }
}

// ---------------------------------------------------------------------------
__global__ __launch_bounds__(256) void conv_silu(
    const float* __restrict__ xz, const float* __restrict__ cw,
    const float* __restrict__ cb, float* __restrict__ xc)
{
    const int g = blockIdx.x * 256 + threadIdx.x;
    const int c4 = g & (DI / 4 - 1);
    const int m = g >> 9;
    const int l = m & (SL - 1);
    const int c = c4 << 2;
    const float4 w0 = *(const float4*)(cw + (size_t)(c + 0) * DCONV);
    const float4 w1 = *(const float4*)(cw + (size_t)(c + 1) * DCONV);
    const float4 w2 = *(const float4*)(cw + (size_t)(c + 2) * DCONV);
    const float4 w3 = *(const float4*)(cw + (size_t)(c + 3) * DCONV);
    float4 acc = *(const float4*)(cb + c);
    #pragma unroll
    for (int j = 0; j < DCONV; ++j) {
        const int lj = l - 3 + j;
        if (lj >= 0) {
            const float4 v = *(const float4*)(xz + (size_t)(m - 3 + j) * NXZ + c);
            acc.x = fmaf(v.x, (&w0.x)[j], acc.x);
            acc.y = fmaf(v.y, (&w1.x)[j], acc.y);
            acc.z = fmaf(v.z, (&w2.x)[j], acc.z);
            acc.w = fmaf(v.w, (&w3.x)[j], acc.w);
        }
    }
    acc.x = acc.x / (1.f + __expf(-acc.x));
    acc.y = acc.y / (1.f + __expf(-acc.y));
    acc.z = acc.z / (1.f + __expf(-acc.z));
    acc.w = acc.w / (1.f + __expf(-acc.w));
    *(float4*)(xc + (size_t)m * DI + c) = acc;
}

// ---------------------------------------------------------------------------
// Selective scan v2: transposed LDS ([ch][t] / [s][t], b128 4-t reads) +
// DPP 16-lane reduce (VALU pipe) replacing shfl_xor (DS pipe).
__global__ __launch_bounds__(256) void scan_k(
    const float* u,                 // xc [M, DI]
    const float* __restrict__ dbc,  // [M, 96]: B 64..79, C 80..95
    const float* __restrict__ xz,   // delta at col c, z at col DI+c
    float* y,                       // = xc (aliased with u)
    const float* __restrict__ Alog, // [DI, DS] layer slice
    const float* __restrict__ Dl)   // [DI]
{
    const int b = blockIdx.y;
    const int c0 = blockIdx.x * 16;
    const int tid = threadIdx.x;
    const int ch = tid >> 4;       // 0..15; 4 per wave; DPP row = one ch
    const int s = tid & 15;
    const float Aa = -__expf(Alog[(size_t)(c0 + ch) * DS + s]);
    __shared__ float sdl[16][68];  // [ch][t]
    __shared__ float sxb[16][68];  // [ch][t]  (delta*u)
    __shared__ float sbc[32][68];  // [s][t] B rows 0..15, C rows 16..31
    __shared__ float sp0[64][17];  // [t][ch]  u*D*silu(z)
    __shared__ float sp1[64][17];  // [t][ch]  silu(z)
    __shared__ float sy[64][16];
    __shared__ float sD[16];
    if (tid < 16) sD[tid] = Dl[c0 + tid];
    __syncthreads();
    float h = 0.f;
    const int row = tid >> 2;
    const int q = (tid & 3) << 2;
    for (int t0b = 0; t0b < SL; t0b += 64) {
        const size_t mb = (size_t)b * SL + t0b;
        const float4 dlv = *(const float4*)(xz + (mb + row) * NXZ + c0 + q);
        const float4 uv  = *(const float4*)(u  + (mb + row) * DI + c0 + q);
        const float4 zv  = *(const float4*)(xz + (mb + row) * NXZ + DI + c0 + q);
        float4 p0, p1;
        #pragma unroll
        for (int j = 0; j < 4; ++j) {
            const float dl = (&dlv.x)[j], uu = (&uv.x)[j], zz = (&zv.x)[j];
            const float w = zz / (1.f + __expf(-zz));
            sdl[q + j][row] = dl;
            sxb[q + j][row] = dl * uu;
            (&p1.x)[j] = w;
            (&p0.x)[j] = uu * sD[q + j] * w;
        }
        *(float4*)&sp0[row][q] = p0;
        *(float4*)&sp1[row][q] = p1;
        #pragma unroll
        for (int p = 0; p < 2; ++p) {
            const int idx = p * 256 + tid;
            const int r2 = idx >> 3, q2 = (idx & 7) << 2;
            const float4 v = *(const float4*)(dbc + (mb + r2) * NDBC + DTR + q2);
            sbc[q2 + 0][r2] = v.x; sbc[q2 + 1][r2] = v.y;
            sbc[q2 + 2][r2] = v.z; sbc[q2 + 3][r2] = v.w;
        }
        __syncthreads();
        for (int it = 0; it < 16; ++it) {
            const int t0 = it * 4;
            const float4 dl4 = *(const float4*)&sdl[ch][t0];
            const float4 xb4 = *(const float4*)&sxb[ch][t0];
            const float4 B4  = *(const float4*)&sbc[s][t0];
            const float4 C4  = *(const float4*)&sbc[16 + s][t0];
            float py0, py1, py2, py3;
            {
                const float dA = __expf(dl4.x * Aa);
                h = fmaf(dA, h, xb4.x * B4.x);
                float p = h * C4.x;
                p = dpp_radd<0xB1>(p);  p = dpp_radd<0x4E>(p);
                p = dpp_radd<0x124>(p); p = dpp_radd<0x128>(p);
                py0 = p;
            }
            {
                const float dA = __expf(dl4.y * Aa);
                h = fmaf(dA, h, xb4.y * B4.y);
                float p = h * C4.y;
                p = dpp_radd<0xB1>(p);  p = dpp_radd<0x4E>(p);
                p = dpp_radd<0x124>(p); p = dpp_radd<0x128>(p);
                py1 = p;
            }
            {
                const float dA = __expf(dl4.z * Aa);
                h = fmaf(dA, h, xb4.z * B4.z);
                float p = h * C4.z;
                p = dpp_radd<0xB1>(p);  p = dpp_radd<0x4E>(p);
                p = dpp_radd<0x124>(p); p = dpp_radd<0x128>(p);
                py2 = p;
            }
            {
                const float dA = __expf(dl4.w * Aa);
                h = fmaf(dA, h, xb4.w * B4.w);
                float p = h * C4.w;
                p = dpp_radd<0xB1>(p);  p = dpp_radd<0x4E>(p);
                p = dpp_radd<0x124>(p); p = dpp_radd<0x128>(p);
                py3 = p;
            }
            if (s < 4) {
                const int t = t0 + s;
                const float lo_ = (s & 1) ? py1 : py0;
                const float hi_ = (s & 1) ? py3 : py2;
                const float pysel = (s & 2) ? hi_ : lo_;
                sy[t][ch] = fmaf(pysel, sp1[t][ch], sp0[t][ch]);
            }
        }
        __syncthreads();
        *(float4*)(y + (mb + row) * DI + c0 + q) = *(const float4*)&sy[row][q];
        __syncthreads();
    }
}

// ---------------------------------------------------------------------------
extern "C" void kernel_launch(void* const* d_in, const int* in_sizes, int n_in,
                              void* d_out, int out_size, void* d_ws, size_t ws_size,
                              hipStream_t stream)
{
    const float* x0   = (const float*)d_in[0];
    const float* in_w = (const float*)d_in[1];
    const float* cw   = (const float*)d_in[2];
    const float* cb   = (const float*)d_in[3];
    const float* xpw  = (const float*)d_in[4];
    const float* dtw  = (const float*)d_in[5];
    const float* dtb  = (const float*)d_in[6];
    const float* Alog = (const float*)d_in[7];
    const float* Dp   = (const float*)d_in[8];
    const float* ow   = (const float*)d_in[9];
    float* xbuf = (float*)d_out;  // inter-layer x lives in d_out (MT*DIMK)

    const size_t perB = (size_t)SL * (NXZ + DI + NDBC) * sizeof(float); // ~51.1MB
    int nbc = 1;
    if (ws_size >= perB * 4) nbc = 4;
    else if (ws_size >= perB * 2) nbc = 2;
    else if (ws_size < perB) return;
    const int nchunks = NB / nbc;
    const int M = nbc * SL;

    float* xz  = (float*)d_ws;                 // [M, NXZ]; xi half reused as delta
    float* xc  = xz + (size_t)M * NXZ;         // [M, DI];  reused as y
    float* dbc = xc + (size_t)M * DI;          // [M, NDBC]

    const dim3 blk(256);
    for (int ly = 0; ly < NDEPTH; ++ly) {
        const float* Wi   = in_w + (size_t)ly * NXZ * DIMK;
        const float* cwl  = cw   + (size_t)ly * DI * DCONV;
        const float* cbl  = cb   + (size_t)ly * DI;
        const float* xpl  = xpw  + (size_t)ly * NDBC * DI;
        const float* dtwl = dtw  + (size_t)ly * DI * DTR;
        const float* dtbl = dtb  + (size_t)ly * DI;
        const float* Al   = Alog + (size_t)ly * DI * DS;
        const float* Dl   = Dp   + (size_t)ly * DI;
        const float* owl  = ow   + (size_t)ly * DIMK * DI;

        for (int ck = 0; ck < nchunks; ++ck) {
            const float* xin = (ly == 0 ? x0 : xbuf) + (size_t)ck * M * DIMK;
            float* xdst = xbuf + (size_t)ck * M * DIMK;
            // 1. xz = x @ Wi^T  (bf16 MFMA)
            gemm_mfma<<<dim3(NXZ / 128, M / 128), blk, 0, stream>>>(
                xin, Wi, xz, DIMK, DIMK, NXZ);
            // 2. xc = silu(causal depthwise conv(xi) + cb)
            conv_silu<<<dim3(M * (DI / 4) / 256), blk, 0, stream>>>(xz, cwl, cbl, xc);
            // 3. dbc = xc @ xp^T  (split-bf16 MFMA, ~fp32 accuracy)
            gemm_xproj<<<dim3(3, M / 128), blk, 0, stream>>>(
                xc, xpl, dbc, DI, DI);
            // 4. delta = softplus(dt @ dtw^T + dtb) -> xi half of xz
            gemm_delta<<<dim3(DI / 128, M / 128), blk, 0, stream>>>(
                dbc, dtwl, xz, dtbl);
            // 5. scan; y -> xc
            scan_k<<<dim3(DI / 16, nbc), blk, 0, stream>>>(
                xc, dbc, xz, xc, Al, Dl);
            // 6. x_next = y @ ow^T  (bf16 MFMA)
            gemm_mfma<<<dim3(DIMK / 128, M / 128), blk, 0, stream>>>(
                xc, owl, xdst, DI, DI, DIMK);
        }
    }
}

// Round 5
// 2233.624 us; speedup vs baseline: 5.4522x; 1.2612x over previous
//
#include <hip/hip_runtime.h>
#include <hip/hip_bf16.h>
#include <math.h>

#define DIMK 1024
#define NDEPTH 4
#define DS 16
#define DCONV 4
#define DI 2048
#define DTR 64
#define NB 4
#define SL 2048
#define MT (NB * SL)        // 8192
#define NXZ (2 * DI)        // 4096
#define NDBC (DTR + 2 * DS) // 96

typedef float f32x4 __attribute__((ext_vector_type(4)));
typedef short short8 __attribute__((ext_vector_type(8)));
typedef short short4v __attribute__((ext_vector_type(4)));

__device__ inline unsigned short f2bf(float f) {
    unsigned u = __builtin_bit_cast(unsigned, f);
    unsigned r = (u + 0x7FFFu + ((u >> 16) & 1u)) >> 16;
    return (unsigned short)r;
}
__device__ inline float bf2f(unsigned short h) {
    unsigned u = ((unsigned)h) << 16;
    return __builtin_bit_cast(float, u);
}
__device__ inline void split_bf(float f, unsigned short& hi, unsigned short& lo) {
    hi = f2bf(f);
    lo = f2bf(f - bf2f(hi));
}
__device__ inline unsigned short cvt1(float f) {
    __hip_bfloat16 t = __float2bfloat16(f);
    return __builtin_bit_cast(unsigned short, t);
}
__device__ inline void mfma16(f32x4& d, short8 a, short8 b) {
    asm volatile("v_mfma_f32_16x16x32_bf16 %0, %1, %2, %0"
                 : "+v"(d) : "v"(a), "v"(b));
}
template <int CTRL>
__device__ inline float dpp_radd(float v) {
    int x = __builtin_bit_cast(int, v);
    int m = __builtin_amdgcn_update_dpp(0, x, CTRL, 0xF, 0xF, false);
    return v + __builtin_bit_cast(float, m);
}
// async global->LDS, 16 B per lane. LDS dest = wave-uniform base + lane*16.
__device__ __forceinline__ void gload16(const unsigned short* g, unsigned short* l) {
    __builtin_amdgcn_global_load_lds(
        (const __attribute__((address_space(1))) unsigned int*)(g),
        (__attribute__((address_space(3))) unsigned int*)(l),
        16, 0, 0);
}

// ---------------------------------------------------------------------------
// elementwise fp32 -> bf16 (RNE), 4 per thread
__global__ __launch_bounds__(256) void cvt_bf16(
    const float* __restrict__ s, unsigned short* __restrict__ d, int n4)
{
    const int g = blockIdx.x * 256 + threadIdx.x;
    if (g < n4) {
        const float4 f = *(const float4*)(s + (size_t)g * 4);
        short4v v;
        v[0] = (short)cvt1(f.x); v[1] = (short)cvt1(f.y);
        v[2] = (short)cvt1(f.z); v[3] = (short)cvt1(f.w);
        *(short4v*)(d + (size_t)g * 4) = v;
    }
}

// ---------------------------------------------------------------------------
// C[m,n] = sum_k A[m,k]*B[n,k]; A,B bf16 in global, C fp32.
// m97 structure: global_load_lds(16B) staging, pre-swizzled global source,
// linear LDS dest, swizzled ds_read_b128 (same XOR involution both sides).
__global__ __launch_bounds__(256) void gemm_bb(
    const unsigned short* __restrict__ A, const unsigned short* __restrict__ B,
    float* __restrict__ C, int K, int lda, int ldb, int ldc)
{
    __shared__ unsigned short As[128 * 32];
    __shared__ unsigned short Bs[128 * 32];
    const int tid = threadIdx.x;
    const int bm = blockIdx.y * 128, bn = blockIdx.x * 128;
    const int wv = tid >> 6, ln = tid & 63;
    const int wr = wv >> 1, wc = wv & 1;
    const int fr = ln & 15, kg = ln >> 4;
    // staging: wave wv covers rows wv*32..wv*32+31 (2 instrs of 16 rows each)
    const int sr0 = wv * 32 + (ln >> 2);
    const int sr1 = sr0 + 16;
    const int sl = ln & 3;
    const int cg0 = sl ^ ((sr0 >> 1) & 3);
    const int cg1 = sl ^ ((sr1 >> 1) & 3);
    const unsigned short* pa0 = A + (size_t)(bm + sr0) * lda + cg0 * 8;
    const unsigned short* pa1 = A + (size_t)(bm + sr1) * lda + cg1 * 8;
    const unsigned short* pb0 = B + (size_t)(bn + sr0) * ldb + cg0 * 8;
    const unsigned short* pb1 = B + (size_t)(bn + sr1) * ldb + cg1 * 8;
    unsigned short* la0 = As + (wv * 32 + 0) * 32;
    unsigned short* la1 = As + (wv * 32 + 16) * 32;
    unsigned short* lb0 = Bs + (wv * 32 + 0) * 32;
    unsigned short* lb1 = Bs + (wv * 32 + 16) * 32;
    f32x4 acc[4][4] = {};
    for (int k0 = 0; k0 < K; k0 += 32) {
        gload16(pa0 + k0, la0);
        gload16(pa1 + k0, la1);
        gload16(pb0 + k0, lb0);
        gload16(pb1 + k0, lb1);
        __syncthreads();
        short8 af[4], bw[4];
        #pragma unroll
        for (int f = 0; f < 4; ++f) {
            const int ra = wr * 64 + f * 16 + fr;
            af[f] = *(const short8*)&As[ra * 32 + ((kg ^ ((ra >> 1) & 3)) * 8)];
            const int rb = wc * 64 + f * 16 + fr;
            bw[f] = *(const short8*)&Bs[rb * 32 + ((kg ^ ((rb >> 1) & 3)) * 8)];
        }
        #pragma unroll
        for (int fi = 0; fi < 4; ++fi)
            #pragma unroll
            for (int fj = 0; fj < 4; ++fj)
                mfma16(acc[fi][fj], af[fi], bw[fj]);
        __syncthreads();
    }
    #pragma unroll
    for (int fi = 0; fi < 4; ++fi) {
        const int m0 = bm + wr * 64 + fi * 16 + kg * 4;
        #pragma unroll
        for (int fj = 0; fj < 4; ++fj) {
            const int n = bn + wc * 64 + fj * 16 + fr;
            #pragma unroll
            for (int q = 0; q < 4; ++q)
                C[(size_t)(m0 + q) * ldc + n] = acc[fi][fj][q];
        }
    }
}

// ---------------------------------------------------------------------------
// A fp32 (reg-staged + cvt), B bf16 (global_load_lds). CBF: 1 -> bf16 C out.
template <int CBF>
__global__ __launch_bounds__(256) void gemm_fb(
    const float* __restrict__ A, const unsigned short* __restrict__ B,
    void* __restrict__ Cv, int K, int lda, int ldb, int ldc)
{
    __shared__ unsigned short As[128 * 32];
    __shared__ unsigned short Bs[128 * 32];
    const int tid = threadIdx.x;
    const int bm = blockIdx.y * 128, bn = blockIdx.x * 128;
    const int wv = tid >> 6, ln = tid & 63;
    const int wr = wv >> 1, wc = wv & 1;
    const int fr = ln & 15, kg = ln >> 4;
    const int r = tid >> 1, hf = tid & 1;
    const int sr0 = wv * 32 + (ln >> 2);
    const int sr1 = sr0 + 16;
    const int sl = ln & 3;
    const int cg0 = sl ^ ((sr0 >> 1) & 3);
    const int cg1 = sl ^ ((sr1 >> 1) & 3);
    const unsigned short* pb0 = B + (size_t)(bn + sr0) * ldb + cg0 * 8;
    const unsigned short* pb1 = B + (size_t)(bn + sr1) * ldb + cg1 * 8;
    unsigned short* lb0 = Bs + (wv * 32 + 0) * 32;
    unsigned short* lb1 = Bs + (wv * 32 + 16) * 32;
    const float* ga = A + (size_t)(bm + r) * lda + hf * 16;
    f32x4 acc[4][4] = {};
    for (int k0 = 0; k0 < K; k0 += 32) {
        gload16(pb0 + k0, lb0);
        gload16(pb1 + k0, lb1);
        #pragma unroll
        for (int p = 0; p < 2; ++p) {
            const int pk = (2 * hf + p) ^ ((r >> 1) & 3);
            const float4 f0 = *(const float4*)(ga + k0 + p * 8);
            const float4 f1 = *(const float4*)(ga + k0 + p * 8 + 4);
            short8 v;
            v[0] = (short)cvt1(f0.x); v[1] = (short)cvt1(f0.y);
            v[2] = (short)cvt1(f0.z); v[3] = (short)cvt1(f0.w);
            v[4] = (short)cvt1(f1.x); v[5] = (short)cvt1(f1.y);
            v[6] = (short)cvt1(f1.z); v[7] = (short)cvt1(f1.w);
            *(short8*)&As[r * 32 + pk * 8] = v;
        }
        __syncthreads();
        short8 af[4], bw[4];
        #pragma unroll
        for (int f = 0; f < 4; ++f) {
            const int ra = wr * 64 + f * 16 + fr;
            af[f] = *(const short8*)&As[ra * 32 + ((kg ^ ((ra >> 1) & 3)) * 8)];
            const int rb = wc * 64 + f * 16 + fr;
            bw[f] = *(const short8*)&Bs[rb * 32 + ((kg ^ ((rb >> 1) & 3)) * 8)];
        }
        #pragma unroll
        for (int fi = 0; fi < 4; ++fi)
            #pragma unroll
            for (int fj = 0; fj < 4; ++fj)
                mfma16(acc[fi][fj], af[fi], bw[fj]);
        __syncthreads();
    }
    #pragma unroll
    for (int fi = 0; fi < 4; ++fi) {
        const int m0 = bm + wr * 64 + fi * 16 + kg * 4;
        #pragma unroll
        for (int fj = 0; fj < 4; ++fj) {
            const int n = bn + wc * 64 + fj * 16 + fr;
            #pragma unroll
            for (int q = 0; q < 4; ++q) {
                if (CBF) {
                    unsigned short* Cs = (unsigned short*)Cv;
                    Cs[(size_t)(m0 + q) * ldc + n] = cvt1(acc[fi][fj][q]);
                } else {
                    float* Cf = (float*)Cv;
                    Cf[(size_t)(m0 + q) * ldc + n] = acc[fi][fj][q];
                }
            }
        }
    }
}

// ---------------------------------------------------------------------------
// fallback GEMM (round-4 path, fp32 in/out), used only if ws too small
__global__ __launch_bounds__(256) void gemm_mfma(
    const float* __restrict__ A, const float* __restrict__ W,
    float* __restrict__ C, int K, int lda, int ldc)
{
    __shared__ unsigned short As[128 * 32];
    __shared__ unsigned short Ws[128 * 32];
    const int tid = threadIdx.x;
    const int bm = blockIdx.y * 128;
    const int bn = blockIdx.x * 128;
    const int r = tid >> 1;
    const int h = tid & 1;
    const int wv = tid >> 6;
    const int wr = wv >> 1;
    const int wc = wv & 1;
    const int ln = tid & 63;
    const int fr = ln & 15;
    const int kg = ln >> 4;
    f32x4 acc[4][4] = {};
    const float* ga = A + (size_t)(bm + r) * lda + h * 16;
    const float* gw = W + (size_t)(bn + r) * K + h * 16;
    for (int k0 = 0; k0 < K; k0 += 32) {
        #pragma unroll
        for (int p = 0; p < 2; ++p) {
            const int pk = (2 * h + p) ^ ((r >> 1) & 3);
            float4 f0 = *(const float4*)(ga + k0 + p * 8);
            float4 f1 = *(const float4*)(ga + k0 + p * 8 + 4);
            short8 v;
            v[0] = (short)cvt1(f0.x); v[1] = (short)cvt1(f0.y);
            v[2] = (short)cvt1(f0.z); v[3] = (short)cvt1(f0.w);
            v[4] = (short)cvt1(f1.x); v[5] = (short)cvt1(f1.y);
            v[6] = (short)cvt1(f1.z); v[7] = (short)cvt1(f1.w);
            *(short8*)&As[r * 32 + pk * 8] = v;
            f0 = *(const float4*)(gw + k0 + p * 8);
            f1 = *(const float4*)(gw + k0 + p * 8 + 4);
            v[0] = (short)cvt1(f0.x); v[1] = (short)cvt1(f0.y);
            v[2] = (short)cvt1(f0.z); v[3] = (short)cvt1(f0.w);
            v[4] = (short)cvt1(f1.x); v[5] = (short)cvt1(f1.y);
            v[6] = (short)cvt1(f1.z); v[7] = (short)cvt1(f1.w);
            *(short8*)&Ws[r * 32 + pk * 8] = v;
        }
        __syncthreads();
        short8 af[4], bw[4];
        #pragma unroll
        for (int f = 0; f < 4; ++f) {
            const int ra = wr * 64 + f * 16 + fr;
            af[f] = *(const short8*)&As[ra * 32 + ((kg ^ ((ra >> 1) & 3)) * 8)];
            const int rb = wc * 64 + f * 16 + fr;
            bw[f] = *(const short8*)&Ws[rb * 32 + ((kg ^ ((rb >> 1) & 3)) * 8)];
        }
        #pragma unroll
        for (int fi = 0; fi < 4; ++fi)
            #pragma unroll
            for (int fj = 0; fj < 4; ++fj)
                mfma16(acc[fi][fj], af[fi], bw[fj]);
        __syncthreads();
    }
    #pragma unroll
    for (int fi = 0; fi < 4; ++fi) {
        const int m0 = bm + wr * 64 + fi * 16 + kg * 4;
        #pragma unroll
        for (int fj = 0; fj < 4; ++fj) {
            const int n = bn + wc * 64 + fj * 16 + fr;
            #pragma unroll
            for (int q = 0; q < 4; ++q)
                C[(size_t)(m0 + q) * ldc + n] = acc[fi][fj][q];
        }
    }
}

// ---------------------------------------------------------------------------
// dbc = xc @ xp^T, hi/lo-split bf16 MFMA (~fp32 accuracy). BM=128, BN=32.
__global__ __launch_bounds__(256) void gemm_xproj(
    const float* __restrict__ A, const float* __restrict__ W,
    float* __restrict__ C, int K, int lda)
{
    __shared__ unsigned short Ah[128 * 32], Al[128 * 32];
    __shared__ unsigned short Wh[32 * 32], Wl[32 * 32];
    const int tid = threadIdx.x;
    const int bm = blockIdx.y * 128;
    const int bn = blockIdx.x * 32;
    const int r = tid >> 1, hf = tid & 1;
    const int wv = tid >> 6;
    const int ln = tid & 63, fr = ln & 15, kg = ln >> 4;
    const int wsr = tid >> 3;
    const int wc4 = (tid & 7) << 2;
    f32x4 acc[2][2] = {};
    const float* ga = A + (size_t)(bm + r) * lda + hf * 16;
    const float* gw = W + (size_t)(bn + wsr) * K + wc4;
    for (int k0 = 0; k0 < K; k0 += 32) {
        #pragma unroll
        for (int j = 0; j < 4; ++j) {
            const int col = hf * 16 + j * 4;
            const int ad = r * 32 + (((col >> 3) ^ ((r >> 1) & 3)) << 3) + (col & 7);
            const float4 fa = *(const float4*)(ga + k0 + j * 4);
            short4v h4, l4;
            #pragma unroll
            for (int e = 0; e < 4; ++e) {
                unsigned short hh, llo;
                split_bf((&fa.x)[e], hh, llo);
                h4[e] = (short)hh; l4[e] = (short)llo;
            }
            *(short4v*)&Ah[ad] = h4;
            *(short4v*)&Al[ad] = l4;
        }
        {
            const int ad = wsr * 32 + (((wc4 >> 3) ^ ((wsr >> 1) & 3)) << 3) + (wc4 & 7);
            const float4 fw = *(const float4*)(gw + k0);
            short4v h4, l4;
            #pragma unroll
            for (int e = 0; e < 4; ++e) {
                unsigned short hh, llo;
                split_bf((&fw.x)[e], hh, llo);
                h4[e] = (short)hh; l4[e] = (short)llo;
            }
            *(short4v*)&Wh[ad] = h4;
            *(short4v*)&Wl[ad] = l4;
        }
        __syncthreads();
        short8 ah[2], alo[2], bh[2], bl[2];
        #pragma unroll
        for (int f = 0; f < 2; ++f) {
            const int ra = wv * 32 + f * 16 + fr;
            const int ao = ra * 32 + ((kg ^ ((ra >> 1) & 3)) * 8);
            ah[f]  = *(const short8*)&Ah[ao];
            alo[f] = *(const short8*)&Al[ao];
            const int rb = f * 16 + fr;
            const int bo = rb * 32 + ((kg ^ ((rb >> 1) & 3)) * 8);
            bh[f] = *(const short8*)&Wh[bo];
            bl[f] = *(const short8*)&Wl[bo];
        }
        #pragma unroll
        for (int fi = 0; fi < 2; ++fi)
            #pragma unroll
            for (int fj = 0; fj < 2; ++fj) {
                mfma16(acc[fi][fj], ah[fi], bh[fj]);
                mfma16(acc[fi][fj], ah[fi], bl[fj]);
                mfma16(acc[fi][fj], alo[fi], bh[fj]);
            }
        __syncthreads();
    }
    #pragma unroll
    for (int fi = 0; fi < 2; ++fi) {
        const int m0 = bm + wv * 32 + fi * 16 + kg * 4;
        #pragma unroll
        for (int fj = 0; fj < 2; ++fj) {
            const int n = bn + fj * 16 + fr;
            #pragma unroll
            for (int q = 0; q < 4; ++q)
                C[(size_t)(m0 + q) * NDBC + n] = acc[fi][fj][q];
        }
    }
}

// ---------------------------------------------------------------------------
// delta = softplus(dt @ dtw^T + dtb) -> xi half of xz. Split MFMA, K=64.
__global__ __launch_bounds__(256) void gemm_delta(
    const float* __restrict__ A, const float* __restrict__ W,
    float* __restrict__ C, const float* __restrict__ bias)
{
    __shared__ unsigned short Ah[128 * 32], Al[128 * 32];
    __shared__ unsigned short Wh[128 * 32], Wl[128 * 32];
    const int tid = threadIdx.x;
    const int bm = blockIdx.y * 128;
    const int bn = blockIdx.x * 128;
    const int r = tid >> 1, hf = tid & 1;
    const int wv = tid >> 6, wr = wv >> 1, wc = wv & 1;
    const int ln = tid & 63, fr = ln & 15, kg = ln >> 4;
    f32x4 acc[4][4] = {};
    const float* ga = A + (size_t)(bm + r) * NDBC + hf * 16;
    const float* gw = W + (size_t)(bn + r) * DTR + hf * 16;
    for (int k0 = 0; k0 < DTR; k0 += 32) {
        #pragma unroll
        for (int j = 0; j < 4; ++j) {
            const int col = hf * 16 + j * 4;
            const int ad = r * 32 + (((col >> 3) ^ ((r >> 1) & 3)) << 3) + (col & 7);
            const float4 fa = *(const float4*)(ga + k0 + j * 4);
            const float4 fw = *(const float4*)(gw + k0 + j * 4);
            short4v ah4, al4, wh4, wl4;
            #pragma unroll
            for (int e = 0; e < 4; ++e) {
                unsigned short hh, llo;
                split_bf((&fa.x)[e], hh, llo);
                ah4[e] = (short)hh; al4[e] = (short)llo;
                split_bf((&fw.x)[e], hh, llo);
                wh4[e] = (short)hh; wl4[e] = (short)llo;
            }
            *(short4v*)&Ah[ad] = ah4; *(short4v*)&Al[ad] = al4;
            *(short4v*)&Wh[ad] = wh4; *(short4v*)&Wl[ad] = wl4;
        }
        __syncthreads();
        short8 ah[4], alo[4], bh[4], bl[4];
        #pragma unroll
        for (int f = 0; f < 4; ++f) {
            const int ra = wr * 64 + f * 16 + fr;
            const int ao = ra * 32 + ((kg ^ ((ra >> 1) & 3)) * 8);
            ah[f]  = *(const short8*)&Ah[ao];
            alo[f] = *(const short8*)&Al[ao];
            const int rb = wc * 64 + f * 16 + fr;
            const int bo = rb * 32 + ((kg ^ ((rb >> 1) & 3)) * 8);
            bh[f] = *(const short8*)&Wh[bo];
            bl[f] = *(const short8*)&Wl[bo];
        }
        #pragma unroll
        for (int fi = 0; fi < 4; ++fi)
            #pragma unroll
            for (int fj = 0; fj < 4; ++fj) {
                mfma16(acc[fi][fj], ah[fi], bh[fj]);
                mfma16(acc[fi][fj], ah[fi], bl[fj]);
                mfma16(acc[fi][fj], alo[fi], bh[fj]);
            }
        __syncthreads();
    }
    #pragma unroll
    for (int fi = 0; fi < 4; ++fi) {
        const int m0 = bm + wr * 64 + fi * 16 + kg * 4;
        #pragma unroll
        for (int fj = 0; fj < 4; ++fj) {
            const int n = bn + wc * 64 + fj * 16 + fr;
            const float bb = bias[n];
            #pragma unroll
            for (int q = 0; q < 4; ++q) {
                float v = acc[fi][fj][q] + bb;
                v = (v > 20.f) ? v : log1pf(__expf(v));
                C[(size_t)(m0 + q) * NXZ + n] = v;
            }
        }
    }
}

// ---------------------------------------------------------------------------
__global__ __launch_bounds__(256) void conv_silu(
    const float* __restrict__ xz, const float* __restrict__ cw,
    const float* __restrict__ cb, float* __restrict__ xc)
{
    const int g = blockIdx.x * 256 + threadIdx.x;
    const int c4 = g & (DI / 4 - 1);
    const int m = g >> 9;
    const int l = m & (SL - 1);
    const int c = c4 << 2;
    const float4 w0 = *(const float4*)(cw + (size_t)(c + 0) * DCONV);
    const float4 w1 = *(const float4*)(cw + (size_t)(c + 1) * DCONV);
    const float4 w2 = *(const float4*)(cw + (size_t)(c + 2) * DCONV);
    const float4 w3 = *(const float4*)(cw + (size_t)(c + 3) * DCONV);
    float4 acc = *(const float4*)(cb + c);
    #pragma unroll
    for (int j = 0; j < DCONV; ++j) {
        const int lj = l - 3 + j;
        if (lj >= 0) {
            const float4 v = *(const float4*)(xz + (size_t)(m - 3 + j) * NXZ + c);
            acc.x = fmaf(v.x, (&w0.x)[j], acc.x);
            acc.y = fmaf(v.y, (&w1.x)[j], acc.y);
            acc.z = fmaf(v.z, (&w2.x)[j], acc.z);
            acc.w = fmaf(v.w, (&w3.x)[j], acc.w);
        }
    }
    acc.x = acc.x / (1.f + __expf(-acc.x));
    acc.y = acc.y / (1.f + __expf(-acc.y));
    acc.z = acc.z / (1.f + __expf(-acc.z));
    acc.w = acc.w / (1.f + __expf(-acc.w));
    *(float4*)(xc + (size_t)m * DI + c) = acc;
}

// ---------------------------------------------------------------------------
// Selective scan (round-4 version, unchanged)
__global__ __launch_bounds__(256) void scan_k(
    const float* u, const float* __restrict__ dbc,
    const float* __restrict__ xz, float* y,
    const float* __restrict__ Alog, const float* __restrict__ Dl)
{
    const int b = blockIdx.y;
    const int c0 = blockIdx.x * 16;
    const int tid = threadIdx.x;
    const int ch = tid >> 4;
    const int s = tid & 15;
    const float Aa = -__expf(Alog[(size_t)(c0 + ch) * DS + s]);
    __shared__ float sdl[16][68];
    __shared__ float sxb[16][68];
    __shared__ float sbc[32][68];
    __shared__ float sp0[64][17];
    __shared__ float sp1[64][17];
    __shared__ float sy[64][16];
    __shared__ float sD[16];
    if (tid < 16) sD[tid] = Dl[c0 + tid];
    __syncthreads();
    float h = 0.f;
    const int row = tid >> 2;
    const int q = (tid & 3) << 2;
    for (int t0b = 0; t0b < SL; t0b += 64) {
        const size_t mb = (size_t)b * SL + t0b;
        const float4 dlv = *(const float4*)(xz + (mb + row) * NXZ + c0 + q);
        const float4 uv  = *(const float4*)(u  + (mb + row) * DI + c0 + q);
        const float4 zv  = *(const float4*)(xz + (mb + row) * NXZ + DI + c0 + q);
        float4 p0, p1;
        #pragma unroll
        for (int j = 0; j < 4; ++j) {
            const float dl = (&dlv.x)[j], uu = (&uv.x)[j], zz = (&zv.x)[j];
            const float w = zz / (1.f + __expf(-zz));
            sdl[q + j][row] = dl;
            sxb[q + j][row] = dl * uu;
            (&p1.x)[j] = w;
            (&p0.x)[j] = uu * sD[q + j] * w;
        }
        *(float4*)&sp0[row][q] = p0;
        *(float4*)&sp1[row][q] = p1;
        #pragma unroll
        for (int p = 0; p < 2; ++p) {
            const int idx = p * 256 + tid;
            const int r2 = idx >> 3, q2 = (idx & 7) << 2;
            const float4 v = *(const float4*)(dbc + (mb + r2) * NDBC + DTR + q2);
            sbc[q2 + 0][r2] = v.x; sbc[q2 + 1][r2] = v.y;
            sbc[q2 + 2][r2] = v.z; sbc[q2 + 3][r2] = v.w;
        }
        __syncthreads();
        for (int it = 0; it < 16; ++it) {
            const int t0 = it * 4;
            const float4 dl4 = *(const float4*)&sdl[ch][t0];
            const float4 xb4 = *(const float4*)&sxb[ch][t0];
            const float4 B4  = *(const float4*)&sbc[s][t0];
            const float4 C4  = *(const float4*)&sbc[16 + s][t0];
            float py0, py1, py2, py3;
            {
                const float dA = __expf(dl4.x * Aa);
                h = fmaf(dA, h, xb4.x * B4.x);
                float p = h * C4.x;
                p = dpp_radd<0xB1>(p);  p = dpp_radd<0x4E>(p);
                p = dpp_radd<0x124>(p); p = dpp_radd<0x128>(p);
                py0 = p;
            }
            {
                const float dA = __expf(dl4.y * Aa);
                h = fmaf(dA, h, xb4.y * B4.y);
                float p = h * C4.y;
                p = dpp_radd<0xB1>(p);  p = dpp_radd<0x4E>(p);
                p = dpp_radd<0x124>(p); p = dpp_radd<0x128>(p);
                py1 = p;
            }
            {
                const float dA = __expf(dl4.z * Aa);
                h = fmaf(dA, h, xb4.z * B4.z);
                float p = h * C4.z;
                p = dpp_radd<0xB1>(p);  p = dpp_radd<0x4E>(p);
                p = dpp_radd<0x124>(p); p = dpp_radd<0x128>(p);
                py2 = p;
            }
            {
                const float dA = __expf(dl4.w * Aa);
                h = fmaf(dA, h, xb4.w * B4.w);
                float p = h * C4.w;
                p = dpp_radd<0xB1>(p);  p = dpp_radd<0x4E>(p);
                p = dpp_radd<0x124>(p); p = dpp_radd<0x128>(p);
                py3 = p;
            }
            if (s < 4) {
                const int t = t0 + s;
                const float lo_ = (s & 1) ? py1 : py0;
                const float hi_ = (s & 1) ? py3 : py2;
                const float pysel = (s & 2) ? hi_ : lo_;
                sy[t][ch] = fmaf(pysel, sp1[t][ch], sp0[t][ch]);
            }
        }
        __syncthreads();
        *(float4*)(y + (mb + row) * DI + c0 + q) = *(const float4*)&sy[row][q];
        __syncthreads();
    }
}

// ---------------------------------------------------------------------------
extern "C" void kernel_launch(void* const* d_in, const int* in_sizes, int n_in,
                              void* d_out, int out_size, void* d_ws, size_t ws_size,
                              hipStream_t stream)
{
    const float* x0   = (const float*)d_in[0];
    const float* in_w = (const float*)d_in[1];
    const float* cw   = (const float*)d_in[2];
    const float* cb   = (const float*)d_in[3];
    const float* xpw  = (const float*)d_in[4];
    const float* dtw  = (const float*)d_in[5];
    const float* dtb  = (const float*)d_in[6];
    const float* Alog = (const float*)d_in[7];
    const float* Dp   = (const float*)d_in[8];
    const float* ow   = (const float*)d_in[9];

    const size_t perB = (size_t)SL * (NXZ + DI + NDBC) * sizeof(float); // ~51.1MB
    const size_t wby  = ((size_t)NXZ * DIMK + (size_t)DIMK * DI) * 2;   // 12.6MB
    int nbc = 0, fast = 0;
    if (ws_size >= 4 * perB + wby)      { nbc = 4; fast = 1; }
    else if (ws_size >= 2 * perB + wby) { nbc = 2; fast = 1; }
    else if (ws_size >= perB + wby)     { nbc = 1; fast = 1; }
    else if (ws_size >= 4 * perB)       { nbc = 4; }
    else if (ws_size >= 2 * perB)       { nbc = 2; }
    else if (ws_size >= perB)           { nbc = 1; }
    else return;
    const int nchunks = NB / nbc;
    const int M = nbc * SL;

    float* xz  = (float*)d_ws;                 // [M, NXZ]; xi half reused as delta
    float* xc  = xz + (size_t)M * NXZ;         // [M, DI];  reused as y
    float* dbc = xc + (size_t)M * DI;          // [M, NDBC]
    unsigned short* wi16 = (unsigned short*)(dbc + (size_t)M * NDBC);
    unsigned short* ow16 = wi16 + (size_t)NXZ * DIMK;

    // bf16 inter-layer x lives in the second half of d_out (16.8 of 33.5 MB)
    unsigned short* xb16 = (unsigned short*)d_out + (size_t)MT * DIMK;
    float* xbuf = (float*)d_out;  // fallback fp32 inter-layer x

    const dim3 blk(256);
    if (fast) {
        const int n4x = MT * DIMK / 4;
        cvt_bf16<<<dim3(n4x / 256), blk, 0, stream>>>(x0, xb16, n4x);
    }
    for (int ly = 0; ly < NDEPTH; ++ly) {
        const float* Wi   = in_w + (size_t)ly * NXZ * DIMK;
        const float* cwl  = cw   + (size_t)ly * DI * DCONV;
        const float* cbl  = cb   + (size_t)ly * DI;
        const float* xpl  = xpw  + (size_t)ly * NDBC * DI;
        const float* dtwl = dtw  + (size_t)ly * DI * DTR;
        const float* dtbl = dtb  + (size_t)ly * DI;
        const float* Al   = Alog + (size_t)ly * DI * DS;
        const float* Dl   = Dp   + (size_t)ly * DI;
        const float* owl  = ow   + (size_t)ly * DIMK * DI;

        if (fast) {
            const int n4w = NXZ * DIMK / 4;
            cvt_bf16<<<dim3(n4w / 256), blk, 0, stream>>>(Wi, wi16, n4w);
            const int n4o = DIMK * DI / 4;
            cvt_bf16<<<dim3(n4o / 256), blk, 0, stream>>>(owl, ow16, n4o);
        }

        for (int ck = 0; ck < nchunks; ++ck) {
            if (fast) {
                const unsigned short* xin16 = xb16 + (size_t)ck * M * DIMK;
                // 1. xz = x @ Wi^T  (bf16 x bf16 MFMA, global_load_lds)
                gemm_bb<<<dim3(NXZ / 128, M / 128), blk, 0, stream>>>(
                    xin16, wi16, xz, DIMK, DIMK, DIMK, NXZ);
            } else {
                const float* xin = (ly == 0 ? x0 : xbuf) + (size_t)ck * M * DIMK;
                gemm_mfma<<<dim3(NXZ / 128, M / 128), blk, 0, stream>>>(
                    xin, Wi, xz, DIMK, DIMK, NXZ);
            }
            // 2. xc = silu(causal depthwise conv(xi) + cb)
            conv_silu<<<dim3(M * (DI / 4) / 256), blk, 0, stream>>>(xz, cwl, cbl, xc);
            // 3. dbc = xc @ xp^T  (split-bf16 MFMA)
            gemm_xproj<<<dim3(3, M / 128), blk, 0, stream>>>(
                xc, xpl, dbc, DI, DI);
            // 4. delta = softplus(dt @ dtw^T + dtb) -> xi half of xz
            gemm_delta<<<dim3(DI / 128, M / 128), blk, 0, stream>>>(
                dbc, dtwl, xz, dtbl);
            // 5. scan; y -> xc
            scan_k<<<dim3(DI / 16, nbc), blk, 0, stream>>>(
                xc, dbc, xz, xc, Al, Dl);
            // 6. x_next = y @ ow^T
            if (fast) {
                if (ly < NDEPTH - 1) {
                    gemm_fb<1><<<dim3(DIMK / 128, M / 128), blk, 0, stream>>>(
                        xc, ow16, xb16 + (size_t)ck * M * DIMK, DI, DI, DI, DIMK);
                } else {
                    gemm_fb<0><<<dim3(DIMK / 128, M / 128), blk, 0, stream>>>(
                        xc, ow16, (float*)d_out + (size_t)ck * M * DIMK,
                        DI, DI, DI, DIMK);
                }
            } else {
                float* xdst = (ly == NDEPTH - 1 ? (float*)d_out : xbuf) +
                              (size_t)ck * M * DIMK;
                gemm_mfma<<<dim3(DIMK / 128, M / 128), blk, 0, stream>>>(
                    xc, owl, xdst, DI, DI, DIMK);
            }
        }
    }
}